// Round 1
// baseline (26282.687 us; speedup 1.0000x reference)
//
#include <hip/hip_runtime.h>
#include <hip/hip_cooperative_groups.h>
#include <math.h>

namespace cg = cooperative_groups;

#define T_STEPS 256
#define BATCH 64
#define DIN 256
#define DSTATE 512
#define NGATE 2048   // 4*DSTATE
#define NCLS 10000
#define ROWS 16384   // T_STEPS*BATCH

// Permute gate columns: out[k][s*4+g] = in[k][g*512+s]
// so that all 4 gates of a state index land in one 32-wide column tile.
__global__ void permute_gates(const float* __restrict__ in, float* __restrict__ out, int K) {
    int e = blockIdx.x * 256 + threadIdx.x;
    if (e >= K * NGATE) return;
    int k = e >> 11;           // /2048
    int jp = e & 2047;
    int s = jp >> 2, g = jp & 3;
    out[e] = in[k * NGATE + g * DSTATE + s];
}

// Cooperative LSTM scan. 256 blocks x 512 threads.
// Block = (b_tile 0..3 [16 batches], j_tile 0..63 [32 permuted gate cols = 8 states x 4 gates])
// One grid.sync() per timestep. Cell state c lives in registers (threads 0..127).
__launch_bounds__(512)
__global__ void lstm_scan(const float* __restrict__ x,    // [T][B][DIN]
                          const float* __restrict__ h0,   // [B][DSTATE]
                          const float* __restrict__ c0,   // [B][DSTATE]
                          const float* __restrict__ Wxp,  // [DIN][NGATE] permuted
                          const float* __restrict__ Whp,  // [DSTATE][NGATE] permuted
                          const float* __restrict__ bp,   // [NGATE] permuted
                          float* __restrict__ hs) {       // [T][B][DSTATE]
    cg::grid_group grid = cg::this_grid();
    __shared__ float xT[DIN][17];     // xT[k][b_local]
    __shared__ float hT[DSTATE][17];  // hT[k][b_local]
    __shared__ float zb[16][32];      // z[b_local][j_local]
    const int tid = threadIdx.x;
    const int bid = blockIdx.x;
    const int b0 = (bid >> 6) * 16;
    const int j_tile = bid & 63;
    const int j0 = j_tile * 32;   // permuted column base (= s0*4)
    const int s0 = j_tile * 8;    // state base
    const int jl = tid & 31;
    const int bl = tid >> 5;      // 0..15
    const int jp = j0 + jl;
    const float bias = bp[jp];

    float c_reg = 0.f;
    int gb = 0, gs = 0, zbl = 0, sl = 0;
    if (tid < 128) {
        zbl = tid >> 3; sl = tid & 7;
        gb = b0 + zbl; gs = s0 + sl;
        c_reg = c0[gb * DSTATE + gs];
    }

    for (int t = 0; t < T_STEPS; ++t) {
        const float* hsrc = (t == 0) ? h0 : (hs + (size_t)(t - 1) * BATCH * DSTATE);
        // stage x_t[b0..b0+15][:] transposed into LDS (4096 floats)
        #pragma unroll
        for (int r = 0; r < 8; ++r) {
            int e = r * 512 + tid;
            int xb = e >> 8, k = e & 255;
            xT[k][xb] = x[((size_t)t * BATCH + b0 + xb) * DIN + k];
        }
        // stage h_{t-1}[b0..b0+15][:] transposed (8192 floats)
        #pragma unroll
        for (int r = 0; r < 16; ++r) {
            int e = r * 512 + tid;
            int hb = e >> 9, k = e & 511;
            hT[k][hb] = hsrc[(size_t)(b0 + hb) * DSTATE + k];
        }
        __syncthreads();

        // z[b][j'] = bias + x.Wx + h.Wh  (4 accumulators to break the FMA chain)
        float a0 = 0.f, a1 = 0.f, a2 = 0.f, a3 = 0.f;
        for (int k = 0; k < DIN; k += 4) {
            a0 += xT[k + 0][bl] * Wxp[(k + 0) * NGATE + jp];
            a1 += xT[k + 1][bl] * Wxp[(k + 1) * NGATE + jp];
            a2 += xT[k + 2][bl] * Wxp[(k + 2) * NGATE + jp];
            a3 += xT[k + 3][bl] * Wxp[(k + 3) * NGATE + jp];
        }
        for (int k = 0; k < DSTATE; k += 4) {
            a0 += hT[k + 0][bl] * Whp[(k + 0) * NGATE + jp];
            a1 += hT[k + 1][bl] * Whp[(k + 1) * NGATE + jp];
            a2 += hT[k + 2][bl] * Whp[(k + 2) * NGATE + jp];
            a3 += hT[k + 3][bl] * Whp[(k + 3) * NGATE + jp];
        }
        zb[bl][jl] = bias + ((a0 + a1) + (a2 + a3));
        __syncthreads();

        // gate phase: threads 0..127 own (b_local, s_local); gates are adjacent cols
        if (tid < 128) {
            float zi = zb[zbl][sl * 4 + 0];
            float zf = zb[zbl][sl * 4 + 1];
            float zg = zb[zbl][sl * 4 + 2];
            float zo = zb[zbl][sl * 4 + 3];
            float ig = 1.f / (1.f + expf(-zi));
            float fg = 1.f / (1.f + expf(-zf));
            float og = 1.f / (1.f + expf(-zo));
            float gg = tanhf(zg);
            c_reg = fg * c_reg + ig * gg;
            float hv = og * tanhf(c_reg);
            hs[((size_t)t * BATCH + gb) * DSTATE + gs] = hv;
        }
        __threadfence();
        grid.sync();
    }
}

// fp32 tiled GEMM: C[ROWS][NCLS] = A[ROWS][DSTATE] * B[DSTATE][NCLS] + bo
// 64x64 tile, 256 threads, 4x4 outputs/thread, K-tile 16.
__launch_bounds__(256)
__global__ void gemm_logits(const float* __restrict__ A,
                            const float* __restrict__ B,
                            const float* __restrict__ bo,
                            float* __restrict__ C) {
    __shared__ float As[16][65];  // As[kk][m]
    __shared__ float Bs[16][68];  // Bs[kk][j]
    const int tid = threadIdx.x;
    const int tx = tid & 15, ty = tid >> 4;
    const int n0 = blockIdx.x * 64;
    const int m0 = blockIdx.y * 64;
    float acc[4][4] = {};
    for (int kt = 0; kt < DSTATE; kt += 16) {
        #pragma unroll
        for (int r = 0; r < 4; ++r) {
            int e = r * 256 + tid;
            int kk = e & 15, m = e >> 4;
            As[kk][m] = A[(size_t)(m0 + m) * DSTATE + kt + kk];
        }
        #pragma unroll
        for (int r = 0; r < 4; ++r) {
            int e = r * 256 + tid;
            int j = e & 63, kk = e >> 6;
            int n = n0 + j;
            Bs[kk][j] = (n < NCLS) ? B[(size_t)(kt + kk) * NCLS + n] : 0.f;
        }
        __syncthreads();
        #pragma unroll
        for (int kk = 0; kk < 16; ++kk) {
            float av[4], bv[4];
            #pragma unroll
            for (int i = 0; i < 4; ++i) av[i] = As[kk][ty * 4 + i];
            #pragma unroll
            for (int j = 0; j < 4; ++j) bv[j] = Bs[kk][tx * 4 + j];
            #pragma unroll
            for (int i = 0; i < 4; ++i)
                #pragma unroll
                for (int j = 0; j < 4; ++j)
                    acc[i][j] += av[i] * bv[j];
        }
        __syncthreads();
    }
    #pragma unroll
    for (int i = 0; i < 4; ++i) {
        int m = m0 + ty * 4 + i;
        #pragma unroll
        for (int j = 0; j < 4; ++j) {
            int n = n0 + tx * 4 + j;
            if (n < NCLS) C[(size_t)m * NCLS + n] = acc[i][j] + bo[n];
        }
    }
}

__device__ inline float wave_reduce_max(float v) {
    #pragma unroll
    for (int off = 32; off > 0; off >>= 1) v = fmaxf(v, __shfl_xor(v, off));
    return v;
}
__device__ inline float wave_reduce_sum(float v) {
    #pragma unroll
    for (int off = 32; off > 0; off >>= 1) v += __shfl_xor(v, off);
    return v;
}

// In-place softmax over each row of logits (=d_out) + per-row CE loss.
// loss_row = (max + log(sum_exp)) - dot(labels, logits)   [uses sum(labels)=1]
__launch_bounds__(256)
__global__ void softmax_loss(float* __restrict__ logits,
                             const float* __restrict__ labels,
                             float* __restrict__ rowloss) {
    __shared__ float sm[4];
    const int tid = threadIdx.x;
    const size_t base = (size_t)blockIdx.x * NCLS;
    float m = -INFINITY;
    for (int c = tid; c < NCLS; c += 256) m = fmaxf(m, logits[base + c]);
    m = wave_reduce_max(m);
    if ((tid & 63) == 0) sm[tid >> 6] = m;
    __syncthreads();
    m = fmaxf(fmaxf(sm[0], sm[1]), fmaxf(sm[2], sm[3]));
    __syncthreads();

    float s = 0.f, dot = 0.f;
    for (int c = tid; c < NCLS; c += 256) {
        float l = logits[base + c];
        s += expf(l - m);
        dot += labels[base + c] * l;
    }
    s = wave_reduce_sum(s);
    if ((tid & 63) == 0) sm[tid >> 6] = s;
    __syncthreads();
    s = sm[0] + sm[1] + sm[2] + sm[3];
    __syncthreads();
    dot = wave_reduce_sum(dot);
    if ((tid & 63) == 0) sm[tid >> 6] = dot;
    __syncthreads();
    dot = sm[0] + sm[1] + sm[2] + sm[3];

    float inv = 1.f / s;
    for (int c = tid; c < NCLS; c += 256)
        logits[base + c] = expf(logits[base + c] - m) * inv;
    if (tid == 0) rowloss[blockIdx.x] = (m + logf(s)) - dot;
}

__launch_bounds__(256)
__global__ void loss_reduce(const float* __restrict__ rowloss, float* __restrict__ out) {
    __shared__ float sm[4];
    float s = 0.f;
    for (int i = threadIdx.x; i < ROWS; i += 256) s += rowloss[i];
    s = wave_reduce_sum(s);
    if ((threadIdx.x & 63) == 0) sm[threadIdx.x >> 6] = s;
    __syncthreads();
    if (threadIdx.x == 0) out[0] = (sm[0] + sm[1] + sm[2] + sm[3]) * (1.f / ROWS);
}

extern "C" void kernel_launch(void* const* d_in, const int* in_sizes, int n_in,
                              void* d_out, int out_size, void* d_ws, size_t ws_size,
                              hipStream_t stream) {
    const float* inputs = (const float*)d_in[0];   // [T][B][DIN]
    const float* labels = (const float*)d_in[1];   // [T][B][NCLS]
    const float* c0     = (const float*)d_in[2];   // initial_state  (cell c)
    const float* h0     = (const float*)d_in[3];   // initial_output (hidden h)
    const float* Wx     = (const float*)d_in[4];   // [DIN][NGATE]
    const float* Wh     = (const float*)d_in[5];   // [DSTATE][NGATE]
    const float* bias   = (const float*)d_in[6];   // [NGATE]
    const float* Wo     = (const float*)d_in[7];   // [DSTATE][NCLS]
    const float* bo     = (const float*)d_in[8];   // [NCLS]
    float* out = (float*)d_out;

    float* ws      = (float*)d_ws;
    float* Wxp     = ws;                       // 524288
    float* Whp     = Wxp + 524288;             // 1048576
    float* bp      = Whp + 1048576;            // 2048
    float* hs      = bp + 2048;                // 8388608  [T][B][DSTATE]
    float* rowloss = hs + 8388608;             // 16384
    // total ws use: ~39.9 MB

    permute_gates<<<(DIN * NGATE + 255) / 256, 256, 0, stream>>>(Wx, Wxp, DIN);
    permute_gates<<<(DSTATE * NGATE + 255) / 256, 256, 0, stream>>>(Wh, Whp, DSTATE);
    permute_gates<<<(NGATE + 255) / 256, 256, 0, stream>>>(bias, bp, 1);

    void* args[] = {(void*)&inputs, (void*)&h0, (void*)&c0,
                    (void*)&Wxp, (void*)&Whp, (void*)&bp, (void*)&hs};
    hipLaunchCooperativeKernel((const void*)lstm_scan, dim3(256), dim3(512),
                               args, 0, stream);

    dim3 g3((NCLS + 63) / 64, ROWS / 64);
    gemm_logits<<<g3, 256, 0, stream>>>(hs, Wo, bo, out);
    softmax_loss<<<ROWS, 256, 0, stream>>>(out, labels, rowloss);
    loss_reduce<<<1, 256, 0, stream>>>(rowloss, out + (size_t)ROWS * NCLS);
}

// Round 2
// 19494.733 us; speedup vs baseline: 1.3482x; 1.3482x over previous
//
#include <hip/hip_runtime.h>
#include <hip/hip_bf16.h>
#include <hip/hip_cooperative_groups.h>
#include <math.h>

namespace cg = cooperative_groups;

#define T_STEPS 256
#define BATCH 64
#define DIN 256
#define DSTATE 512
#define NGATE 2048   // 4*DSTATE
#define NCLS 10000
#define NCLS_PAD 10112   // 79 * 128
#define ROWS 16384   // T_STEPS*BATCH

typedef __attribute__((ext_vector_type(8))) short bf16x8;
typedef __attribute__((ext_vector_type(4))) float f32x4;

__device__ inline unsigned short f2b(float x) {
    __hip_bfloat16 h = __float2bfloat16(x);
    return *(unsigned short*)&h;
}

// Permute gate columns: out[k][s*4+g] = in[k][g*512+s]
__global__ void permute_gates(const float* __restrict__ in, float* __restrict__ out, int K) {
    int e = blockIdx.x * 256 + threadIdx.x;
    if (e >= K * NGATE) return;
    int k = e >> 11;
    int jp = e & 2047;
    int s = jp >> 2, g = jp & 3;
    out[e] = in[k * NGATE + g * DSTATE + s];
}

// Tiled transpose + bf16 convert: WoT[n][k] = bf16(Wo[k][n]), n padded to NCLS_PAD with zeros.
__launch_bounds__(256)
__global__ void transpose_wo(const float* __restrict__ Wo, unsigned short* __restrict__ WoT) {
    __shared__ float tile[64][65];
    const int tid = threadIdx.x;
    const int n0 = blockIdx.x * 64, k0 = blockIdx.y * 64;
    #pragma unroll
    for (int r = 0; r < 16; ++r) {
        int k = (tid >> 6) + r * 4;
        int n = tid & 63;
        float v = (n0 + n < NCLS) ? Wo[(size_t)(k0 + k) * NCLS + n0 + n] : 0.f;
        tile[k][n] = v;
    }
    __syncthreads();
    #pragma unroll
    for (int r = 0; r < 16; ++r) {
        int n = (tid >> 6) + r * 4;
        int k = tid & 63;
        WoT[(size_t)(n0 + n) * DSTATE + k0 + k] = f2b(tile[k][n]);
    }
}

// Cooperative LSTM scan, LDS-resident weights.
// 256 blocks x 512 threads. Block = (b_tile [16 batches], j_tile [32 permuted gate cols]).
__launch_bounds__(512, 1)
__global__ void lstm_scan(const float* __restrict__ x,    // [T][B][DIN]
                          const float* __restrict__ h0,   // [B][DSTATE]
                          const float* __restrict__ c0,   // [B][DSTATE]
                          const float* __restrict__ Wxp,  // [DIN][NGATE] permuted
                          const float* __restrict__ Whp,  // [DSTATE][NGATE] permuted
                          const float* __restrict__ bp,   // [NGATE] permuted
                          float* __restrict__ hs,         // [T][B][DSTATE] fp32
                          unsigned short* __restrict__ hsb) { // same, bf16
    cg::grid_group grid = cg::this_grid();
    __shared__ float Wt[32][772];   // Wt[j_local][k], k = 0..255 Wx rows, 256..767 Wh rows
    __shared__ float xh[16][772];   // xh[b_local][k], same k layout
    __shared__ float zb[16][33];
    const int tid = threadIdx.x;
    const int bid = blockIdx.x;
    const int b0 = (bid >> 6) * 16;
    const int j_tile = bid & 63;
    const int j0 = j_tile * 32;
    const int s0 = j_tile * 8;
    const int jl = tid & 31;
    const int bl = tid >> 5;      // 0..15
    const float bias = bp[j0 + jl];

    // Preload weight slice into LDS (once; weights are step-invariant).
    {
        const int jc = tid & 31;
        const int kb = tid >> 5;  // 0..15
        #pragma unroll
        for (int r = 0; r < 16; ++r) {
            int k = kb + r * 16;                      // 0..255
            Wt[jc][k] = Wxp[(size_t)k * NGATE + j0 + jc];
        }
        #pragma unroll
        for (int r = 0; r < 32; ++r) {
            int k = kb + r * 16;                      // 0..511
            Wt[jc][256 + k] = Whp[(size_t)k * NGATE + j0 + jc];
        }
    }

    float c_reg = 0.f;
    int gb = 0, gs = 0, zbl = 0, sl = 0;
    if (tid < 128) {
        zbl = tid >> 3; sl = tid & 7;
        gb = b0 + zbl; gs = s0 + sl;
        c_reg = c0[gb * DSTATE + gs];
    }

    const float* wrow = &Wt[jl][0];
    const float* xrow = &xh[bl][0];

    for (int t = 0; t < T_STEPS; ++t) {
        const float* hsrc = (t == 0) ? h0 : (hs + (size_t)(t - 1) * BATCH * DSTATE);
        // stage x_t (16x256) and h_{t-1} (16x512) into xh
        #pragma unroll
        for (int r = 0; r < 2; ++r) {
            int e = r * 512 + tid;
            int xb = e >> 6, kq = (e & 63) * 4;      // float4 chunks: 16 rows x 64 chunks
            *(float4*)&xh[xb][kq] = *(const float4*)&x[((size_t)t * BATCH + b0 + xb) * DIN + kq];
        }
        #pragma unroll
        for (int r = 0; r < 4; ++r) {
            int e = r * 512 + tid;
            int hb = e >> 7, kq = (e & 127) * 4;     // 16 rows x 128 chunks
            *(float4*)&xh[hb][256 + kq] = *(const float4*)&hsrc[(size_t)(b0 + hb) * DSTATE + kq];
        }
        __syncthreads();

        float a0 = 0.f, a1 = 0.f, a2 = 0.f, a3 = 0.f;
        #pragma unroll 4
        for (int k = 0; k < 768; k += 8) {
            float4 w0 = *(const float4*)(wrow + k);
            float4 w1 = *(const float4*)(wrow + k + 4);
            float4 v0 = *(const float4*)(xrow + k);
            float4 v1 = *(const float4*)(xrow + k + 4);
            a0 = fmaf(w0.x, v0.x, a0); a1 = fmaf(w0.y, v0.y, a1);
            a2 = fmaf(w0.z, v0.z, a2); a3 = fmaf(w0.w, v0.w, a3);
            a0 = fmaf(w1.x, v1.x, a0); a1 = fmaf(w1.y, v1.y, a1);
            a2 = fmaf(w1.z, v1.z, a2); a3 = fmaf(w1.w, v1.w, a3);
        }
        zb[bl][jl] = bias + ((a0 + a1) + (a2 + a3));
        __syncthreads();

        if (tid < 128) {
            float zi = zb[zbl][sl * 4 + 0];
            float zf = zb[zbl][sl * 4 + 1];
            float zg = zb[zbl][sl * 4 + 2];
            float zo = zb[zbl][sl * 4 + 3];
            float ig = 1.f / (1.f + expf(-zi));
            float fg = 1.f / (1.f + expf(-zf));
            float og = 1.f / (1.f + expf(-zo));
            float gg = tanhf(zg);
            c_reg = fg * c_reg + ig * gg;
            float hv = og * tanhf(c_reg);
            size_t idx = ((size_t)t * BATCH + gb) * DSTATE + gs;
            hs[idx] = hv;
            hsb[idx] = f2b(hv);
        }
        __threadfence();
        grid.sync();
    }
}

// bf16 MFMA GEMM: C[ROWS][NCLS] = A[ROWS][512](bf16) * B^T rows (WoT[n][k], bf16) + bo
// 128x128 tile, BK=32, 256 threads = 4 waves (2x2), each wave 64x64 via 16x16x32 MFMA.
__launch_bounds__(256)
__global__ void gemm_logits_mfma(const unsigned short* __restrict__ A,   // [ROWS][512]
                                 const unsigned short* __restrict__ Bt,  // [NCLS_PAD][512]
                                 const float* __restrict__ bo,
                                 float* __restrict__ C) {
    __shared__ unsigned short As[128][40];   // rows padded to 40 bf16 (80 B)
    __shared__ unsigned short Bs[128][40];
    const int tid = threadIdx.x;
    const int wave = tid >> 6, lane = tid & 63;
    const int wm = wave >> 1, wn = wave & 1;
    const int m0 = blockIdx.y * 128, n0 = blockIdx.x * 128;
    const int g = lane >> 4, mr = lane & 15;

    f32x4 acc[4][4] = {};
    for (int kt = 0; kt < DSTATE; kt += 32) {
        #pragma unroll
        for (int r = 0; r < 2; ++r) {
            int c = r * 256 + tid;          // 512 chunks of 16B
            int row = c >> 2, q = c & 3;
            *(int4*)&As[row][q * 8] = *(const int4*)&A[(size_t)(m0 + row) * DSTATE + kt + q * 8];
            *(int4*)&Bs[row][q * 8] = *(const int4*)&Bt[(size_t)(n0 + row) * DSTATE + kt + q * 8];
        }
        __syncthreads();
        bf16x8 af[4], bf[4];
        #pragma unroll
        for (int f = 0; f < 4; ++f) {
            af[f] = *(const bf16x8*)&As[wm * 64 + f * 16 + mr][g * 8];
            bf[f] = *(const bf16x8*)&Bs[wn * 64 + f * 16 + mr][g * 8];
        }
        #pragma unroll
        for (int fm = 0; fm < 4; ++fm)
            #pragma unroll
            for (int fn = 0; fn < 4; ++fn)
                acc[fm][fn] = __builtin_amdgcn_mfma_f32_16x16x32_bf16(af[fm], bf[fn], acc[fm][fn], 0, 0, 0);
        __syncthreads();
    }
    // C/D layout (m89-verified): col = lane&15, row = (lane>>4)*4 + reg
    #pragma unroll
    for (int fm = 0; fm < 4; ++fm) {
        #pragma unroll
        for (int fn = 0; fn < 4; ++fn) {
            int col = n0 + wn * 64 + fn * 16 + (lane & 15);
            if (col >= NCLS) continue;
            float bias = bo[col];
            #pragma unroll
            for (int r = 0; r < 4; ++r) {
                int row = m0 + wm * 64 + fm * 16 + (lane >> 4) * 4 + r;
                C[(size_t)row * NCLS + col] = acc[fm][fn][r] + bias;
            }
        }
    }
}

__device__ inline float wave_reduce_max(float v) {
    #pragma unroll
    for (int off = 32; off > 0; off >>= 1) v = fmaxf(v, __shfl_xor(v, off));
    return v;
}
__device__ inline float wave_reduce_sum(float v) {
    #pragma unroll
    for (int off = 32; off > 0; off >>= 1) v += __shfl_xor(v, off);
    return v;
}

__launch_bounds__(256)
__global__ void softmax_loss(float* __restrict__ logits,
                             const float* __restrict__ labels,
                             float* __restrict__ rowloss) {
    __shared__ float sm[4];
    const int tid = threadIdx.x;
    const size_t base = (size_t)blockIdx.x * NCLS;
    float m = -INFINITY;
    for (int c = tid; c < NCLS; c += 256) m = fmaxf(m, logits[base + c]);
    m = wave_reduce_max(m);
    if ((tid & 63) == 0) sm[tid >> 6] = m;
    __syncthreads();
    m = fmaxf(fmaxf(sm[0], sm[1]), fmaxf(sm[2], sm[3]));
    __syncthreads();

    float s = 0.f, dot = 0.f;
    for (int c = tid; c < NCLS; c += 256) {
        float l = logits[base + c];
        s += expf(l - m);
        dot += labels[base + c] * l;
    }
    s = wave_reduce_sum(s);
    if ((tid & 63) == 0) sm[tid >> 6] = s;
    __syncthreads();
    s = sm[0] + sm[1] + sm[2] + sm[3];
    __syncthreads();
    dot = wave_reduce_sum(dot);
    if ((tid & 63) == 0) sm[tid >> 6] = dot;
    __syncthreads();
    dot = sm[0] + sm[1] + sm[2] + sm[3];

    float inv = 1.f / s;
    for (int c = tid; c < NCLS; c += 256)
        logits[base + c] = expf(logits[base + c] - m) * inv;
    if (tid == 0) rowloss[blockIdx.x] = (m + logf(s)) - dot;
}

__launch_bounds__(256)
__global__ void loss_reduce(const float* __restrict__ rowloss, float* __restrict__ out) {
    __shared__ float sm[4];
    float s = 0.f;
    for (int i = threadIdx.x; i < ROWS; i += 256) s += rowloss[i];
    s = wave_reduce_sum(s);
    if ((threadIdx.x & 63) == 0) sm[threadIdx.x >> 6] = s;
    __syncthreads();
    if (threadIdx.x == 0) out[0] = (sm[0] + sm[1] + sm[2] + sm[3]) * (1.f / ROWS);
}

extern "C" void kernel_launch(void* const* d_in, const int* in_sizes, int n_in,
                              void* d_out, int out_size, void* d_ws, size_t ws_size,
                              hipStream_t stream) {
    const float* inputs = (const float*)d_in[0];
    const float* labels = (const float*)d_in[1];
    const float* c0     = (const float*)d_in[2];   // initial_state (cell)
    const float* h0     = (const float*)d_in[3];   // initial_output (hidden)
    const float* Wx     = (const float*)d_in[4];
    const float* Wh     = (const float*)d_in[5];
    const float* bias   = (const float*)d_in[6];
    const float* Wo     = (const float*)d_in[7];
    const float* bo     = (const float*)d_in[8];
    float* out = (float*)d_out;

    float* ws      = (float*)d_ws;
    float* Wxp     = ws;                         // 524,288 f
    float* Whp     = Wxp + 524288;               // 1,048,576 f
    float* bp      = Whp + 1048576;              // 2,048 f
    float* hs      = bp + 2048;                  // 8,388,608 f
    float* rowloss = hs + 8388608;               // 16,384 f
    unsigned short* hsb = (unsigned short*)(rowloss + 16384);        // 8,388,608 bf16
    unsigned short* WoT = (unsigned short*)((float*)(rowloss + 16384) + 4194304); // 10112*512 bf16
    // total ws use ~67 MB

    permute_gates<<<(DIN * NGATE + 255) / 256, 256, 0, stream>>>(Wx, Wxp, DIN);
    permute_gates<<<(DSTATE * NGATE + 255) / 256, 256, 0, stream>>>(Wh, Whp, DSTATE);
    permute_gates<<<(NGATE + 255) / 256, 256, 0, stream>>>(bias, bp, 1);
    transpose_wo<<<dim3(NCLS_PAD / 64, DSTATE / 64), 256, 0, stream>>>(Wo, WoT);

    void* args[] = {(void*)&inputs, (void*)&h0, (void*)&c0,
                    (void*)&Wxp, (void*)&Whp, (void*)&bp, (void*)&hs, (void*)&hsb};
    hipLaunchCooperativeKernel((const void*)lstm_scan, dim3(256), dim3(512),
                               args, 0, stream);

    gemm_logits_mfma<<<dim3(NCLS_PAD / 128, ROWS / 128), 256, 0, stream>>>(hsb, WoT, bo, out);
    softmax_loss<<<ROWS, 256, 0, stream>>>(out, labels, rowloss);
    loss_reduce<<<1, 256, 0, stream>>>(rowloss, out + (size_t)ROWS * NCLS);
}

// Round 3
// 3905.162 us; speedup vs baseline: 6.7302x; 4.9920x over previous
//
#include <hip/hip_runtime.h>
#include <hip/hip_bf16.h>
#include <hip/hip_cooperative_groups.h>
#include <math.h>

namespace cg = cooperative_groups;

#define T_STEPS 256
#define BATCH 64
#define DIN 256
#define DSTATE 512
#define NGATE 2048   // 4*DSTATE
#define NCLS 10000
#define NCLS_PAD 10112   // 79 * 128
#define ROWS 16384   // T_STEPS*BATCH

typedef __attribute__((ext_vector_type(8))) short bf16x8;
typedef __attribute__((ext_vector_type(4))) float f32x4;
typedef unsigned short ushort_t;

__device__ inline unsigned short f2b(float x) {
    __hip_bfloat16 h = __float2bfloat16(x);
    return *(unsigned short*)&h;
}
__device__ inline float b2f(unsigned short u) {
    return __uint_as_float(((unsigned int)u) << 16);
}

// ---- prep kernels -------------------------------------------------------

// vectorized f32 -> bf16 (n multiple of 4)
__global__ void f32_to_bf16(const float* __restrict__ in, unsigned short* __restrict__ out, int n4) {
    int i = blockIdx.x * 256 + threadIdx.x;
    if (i >= n4) return;
    float4 v = *(const float4*)&in[i * 4];
    ushort4 o;
    o.x = f2b(v.x); o.y = f2b(v.y); o.z = f2b(v.z); o.w = f2b(v.w);
    *(ushort4*)&out[i * 4] = o;
}

// WT[jp*K + k] = bf16(W[k*2048 + (jp&3)*512 + (jp>>2)])   (permute + transpose + cvt)
__global__ void build_wT(const float* __restrict__ W, unsigned short* __restrict__ WT,
                         int kshift, int total) {
    int e = blockIdx.x * 256 + threadIdx.x;
    if (e >= total) return;
    int jp = e >> kshift;
    int k = e & ((1 << kshift) - 1);
    int s = jp >> 2, g = jp & 3;
    WT[e] = f2b(W[(size_t)k * NGATE + g * DSTATE + s]);
}

__global__ void build_bias(const float* __restrict__ b, float* __restrict__ bp) {
    int jp = blockIdx.x * 256 + threadIdx.x;
    if (jp >= NGATE) return;
    bp[jp] = b[(jp & 3) * DSTATE + (jp >> 2)];
}

// Tiled transpose + bf16 convert: WoT[n][k] = bf16(Wo[k][n]), n padded to NCLS_PAD with zeros.
__launch_bounds__(256)
__global__ void transpose_wo(const float* __restrict__ Wo, unsigned short* __restrict__ WoT) {
    __shared__ float tile[64][65];
    const int tid = threadIdx.x;
    const int n0 = blockIdx.x * 64, k0 = blockIdx.y * 64;
    #pragma unroll
    for (int r = 0; r < 16; ++r) {
        int k = (tid >> 6) + r * 4;
        int n = tid & 63;
        float v = (n0 + n < NCLS) ? Wo[(size_t)(k0 + k) * NCLS + n0 + n] : 0.f;
        tile[k][n] = v;
    }
    __syncthreads();
    #pragma unroll
    for (int r = 0; r < 16; ++r) {
        int n = (tid >> 6) + r * 4;
        int k = tid & 63;
        WoT[(size_t)(n0 + n) * DSTATE + k0 + k] = f2b(tile[k][n]);
    }
}

// ---- Zx = X @ Wx (+bias), output transposed: ZxT[t][jp][b] bf16 ---------
// grid (256 t-blocks, 16 n-tiles of 128), 256 threads = 4 waves.
// Wave w computes all 64 rows x cols [w*32, w*32+32).
__launch_bounds__(256)
__global__ void zx_gemm(const unsigned short* __restrict__ Xb,   // [16384][256]
                        const unsigned short* __restrict__ WxT,  // [2048][256]
                        const float* __restrict__ bp,            // [2048]
                        unsigned short* __restrict__ ZxT) {      // [256][2048][64]
    __shared__ unsigned short As[64][264];
    __shared__ unsigned short Bs[128][264];
    __shared__ float zls[4][32][65];
    const int tid = threadIdx.x;
    const int t = blockIdx.x;
    const int n0 = blockIdx.y * 128;
    const int wave = tid >> 6, lane = tid & 63, mr = lane & 15, g = lane >> 4;

    #pragma unroll
    for (int r = 0; r < 8; ++r) {
        int c = r * 256 + tid; int row = c >> 5, q = c & 31;
        *(int4*)&As[row][q * 8] = *(const int4*)&Xb[((size_t)t * 64 + row) * DIN + q * 8];
    }
    #pragma unroll
    for (int r = 0; r < 16; ++r) {
        int c = r * 256 + tid; int row = c >> 5, q = c & 31;
        *(int4*)&Bs[row][q * 8] = *(const int4*)&WxT[(size_t)(n0 + row) * DIN + q * 8];
    }
    __syncthreads();

    f32x4 acc[4][2] = {};
    #pragma unroll
    for (int kt = 0; kt < DIN; kt += 32) {
        bf16x8 af[4], bf[2];
        #pragma unroll
        for (int fm = 0; fm < 4; ++fm) af[fm] = *(const bf16x8*)&As[fm * 16 + mr][kt + g * 8];
        #pragma unroll
        for (int fn = 0; fn < 2; ++fn) bf[fn] = *(const bf16x8*)&Bs[wave * 32 + fn * 16 + mr][kt + g * 8];
        #pragma unroll
        for (int fm = 0; fm < 4; ++fm)
            #pragma unroll
            for (int fn = 0; fn < 2; ++fn)
                acc[fm][fn] = __builtin_amdgcn_mfma_f32_16x16x32_bf16(af[fm], bf[fn], acc[fm][fn], 0, 0, 0);
    }
    // acc[fm][fn][r] = C[row = fm*16 + g*4 + r][col = fn*16 + mr]; stash transposed in LDS
    #pragma unroll
    for (int fm = 0; fm < 4; ++fm)
        #pragma unroll
        for (int fn = 0; fn < 2; ++fn)
            #pragma unroll
            for (int r = 0; r < 4; ++r)
                zls[wave][fn * 16 + mr][fm * 16 + g * 4 + r] = acc[fm][fn][r];
    // per-wave only -> no barrier; coalesced bf16 stores
    #pragma unroll 4
    for (int jr = 0; jr < 32; ++jr) {
        int j = n0 + wave * 32 + jr;
        float v = zls[wave][jr][lane] + bp[j];
        ZxT[((size_t)t * NGATE + j) * 64 + lane] = f2b(v);
    }
}

// ---- cooperative LSTM scan (MFMA), 64 blocks x 256 threads ---------------
// Block bid owns permuted gate cols [bid*32, bid*32+32) = states [bid*8, bid*8+8), all 64 batches.
__launch_bounds__(256, 1)
__global__ void lstm_scan_mfma(const unsigned short* __restrict__ h0b,  // [64][512] bf16
                               const float* __restrict__ c0,            // [64][512] f32
                               const unsigned short* __restrict__ WhT,  // [2048][512] bf16
                               const unsigned short* __restrict__ ZxT,  // [256][2048][64] bf16
                               unsigned short* __restrict__ hsb) {      // [256][64][512] bf16
    cg::grid_group grid = cg::this_grid();
    __shared__ unsigned short Wl[32][520];
    __shared__ unsigned short hT[64][520];
    __shared__ float zb[64][33];
    const int tid = threadIdx.x;
    const int bid = blockIdx.x;
    const int j0 = bid * 32;
    const int s0 = bid * 8;
    const int wave = tid >> 6, lane = tid & 63, mr = lane & 15, g = lane >> 4;

    // resident Wh slice: 32 rows x 512 bf16
    #pragma unroll
    for (int r = 0; r < 8; ++r) {
        int c = r * 256 + tid; int row = c >> 6, q = c & 63;
        *(int4*)&Wl[row][q * 8] = *(const int4*)&WhT[(size_t)(j0 + row) * DSTATE + q * 8];
    }

    // gate-phase ownership: thread -> batch b = tid>>2, states sl0=(tid&3)*2, sl0+1
    const int gb = tid >> 2;
    const int sl0 = (tid & 3) * 2;
    float creg0 = c0[gb * DSTATE + s0 + sl0];
    float creg1 = c0[gb * DSTATE + s0 + sl0 + 1];
    __syncthreads();

    for (int t = 0; t < T_STEPS; ++t) {
        const unsigned short* hsrc = t ? (hsb + (size_t)(t - 1) * BATCH * DSTATE) : h0b;
        // issue acc-init loads early (Zx slice for this block/step)
        ushort4 za0 = *(const ushort4*)&ZxT[((size_t)t * NGATE + j0 + 0 * 16 + mr) * 64 + wave * 16 + g * 4];
        ushort4 za1 = *(const ushort4*)&ZxT[((size_t)t * NGATE + j0 + 1 * 16 + mr) * 64 + wave * 16 + g * 4];
        // stage h_{t-1}: 64 rows x 512 bf16
        #pragma unroll
        for (int r = 0; r < 16; ++r) {
            int c = r * 256 + tid; int row = c >> 6, q = c & 63;
            *(int4*)&hT[row][q * 8] = *(const int4*)&hsrc[(size_t)row * DSTATE + q * 8];
        }
        __syncthreads();

        f32x4 acc0, acc1;
        acc0[0] = b2f(za0.x); acc0[1] = b2f(za0.y); acc0[2] = b2f(za0.z); acc0[3] = b2f(za0.w);
        acc1[0] = b2f(za1.x); acc1[1] = b2f(za1.y); acc1[2] = b2f(za1.z); acc1[3] = b2f(za1.w);
        #pragma unroll
        for (int kt = 0; kt < DSTATE; kt += 32) {
            bf16x8 af = *(const bf16x8*)&hT[wave * 16 + mr][kt + g * 8];
            acc0 = __builtin_amdgcn_mfma_f32_16x16x32_bf16(af, *(const bf16x8*)&Wl[mr][kt + g * 8], acc0, 0, 0, 0);
            acc1 = __builtin_amdgcn_mfma_f32_16x16x32_bf16(af, *(const bf16x8*)&Wl[16 + mr][kt + g * 8], acc1, 0, 0, 0);
        }
        // z tile: zb[b_local][j_local];  b = wave*16 + g*4 + r, j = fn*16 + mr
        #pragma unroll
        for (int r = 0; r < 4; ++r) {
            zb[wave * 16 + g * 4 + r][mr] = acc0[r];
            zb[wave * 16 + g * 4 + r][16 + mr] = acc1[r];
        }
        // gate phase: each thread's rows are produced by its own wave -> no barrier needed
        {
            float zi0 = zb[gb][sl0 * 4 + 0], zf0 = zb[gb][sl0 * 4 + 1];
            float zg0 = zb[gb][sl0 * 4 + 2], zo0 = zb[gb][sl0 * 4 + 3];
            float zi1 = zb[gb][sl0 * 4 + 4], zf1 = zb[gb][sl0 * 4 + 5];
            float zg1 = zb[gb][sl0 * 4 + 6], zo1 = zb[gb][sl0 * 4 + 7];
            float i0 = 1.f / (1.f + expf(-zi0)), f0 = 1.f / (1.f + expf(-zf0));
            float o0 = 1.f / (1.f + expf(-zo0)), g0 = tanhf(zg0);
            float i1 = 1.f / (1.f + expf(-zi1)), f1 = 1.f / (1.f + expf(-zf1));
            float o1 = 1.f / (1.f + expf(-zo1)), g1 = tanhf(zg1);
            creg0 = f0 * creg0 + i0 * g0;
            creg1 = f1 * creg1 + i1 * g1;
            float h0v = o0 * tanhf(creg0);
            float h1v = o1 * tanhf(creg1);
            ushort2 hv; hv.x = f2b(h0v); hv.y = f2b(h1v);
            *(ushort2*)&hsb[((size_t)t * BATCH + gb) * DSTATE + s0 + sl0] = hv;
        }
        grid.sync();   // provides agent-scope release/acquire for hsb exchange
    }
}

// ---- logits GEMM (unchanged, verified) ----------------------------------
__launch_bounds__(256)
__global__ void gemm_logits_mfma(const unsigned short* __restrict__ A,   // [ROWS][512]
                                 const unsigned short* __restrict__ Bt,  // [NCLS_PAD][512]
                                 const float* __restrict__ bo,
                                 float* __restrict__ C) {
    __shared__ unsigned short As[128][40];
    __shared__ unsigned short Bs[128][40];
    const int tid = threadIdx.x;
    const int wave = tid >> 6, lane = tid & 63;
    const int wm = wave >> 1, wn = wave & 1;
    const int m0 = blockIdx.y * 128, n0 = blockIdx.x * 128;
    const int g = lane >> 4, mr = lane & 15;

    f32x4 acc[4][4] = {};
    for (int kt = 0; kt < DSTATE; kt += 32) {
        #pragma unroll
        for (int r = 0; r < 2; ++r) {
            int c = r * 256 + tid;
            int row = c >> 2, q = c & 3;
            *(int4*)&As[row][q * 8] = *(const int4*)&A[(size_t)(m0 + row) * DSTATE + kt + q * 8];
            *(int4*)&Bs[row][q * 8] = *(const int4*)&Bt[(size_t)(n0 + row) * DSTATE + kt + q * 8];
        }
        __syncthreads();
        bf16x8 af[4], bf[4];
        #pragma unroll
        for (int f = 0; f < 4; ++f) {
            af[f] = *(const bf16x8*)&As[wm * 64 + f * 16 + mr][g * 8];
            bf[f] = *(const bf16x8*)&Bs[wn * 64 + f * 16 + mr][g * 8];
        }
        #pragma unroll
        for (int fm = 0; fm < 4; ++fm)
            #pragma unroll
            for (int fn = 0; fn < 4; ++fn)
                acc[fm][fn] = __builtin_amdgcn_mfma_f32_16x16x32_bf16(af[fm], bf[fn], acc[fm][fn], 0, 0, 0);
        __syncthreads();
    }
    #pragma unroll
    for (int fm = 0; fm < 4; ++fm) {
        #pragma unroll
        for (int fn = 0; fn < 4; ++fn) {
            int col = n0 + wn * 64 + fn * 16 + (lane & 15);
            if (col >= NCLS) continue;
            float bias = bo[col];
            #pragma unroll
            for (int r = 0; r < 4; ++r) {
                int row = m0 + wm * 64 + fm * 16 + (lane >> 4) * 4 + r;
                C[(size_t)row * NCLS + col] = acc[fm][fn][r] + bias;
            }
        }
    }
}

// ---- softmax + loss ------------------------------------------------------
__device__ inline float wave_reduce_max(float v) {
    #pragma unroll
    for (int off = 32; off > 0; off >>= 1) v = fmaxf(v, __shfl_xor(v, off));
    return v;
}
__device__ inline float wave_reduce_sum(float v) {
    #pragma unroll
    for (int off = 32; off > 0; off >>= 1) v += __shfl_xor(v, off);
    return v;
}

__launch_bounds__(256)
__global__ void softmax_loss(float* __restrict__ logits,
                             const float* __restrict__ labels,
                             float* __restrict__ rowloss) {
    __shared__ float sm[4];
    const int tid = threadIdx.x;
    const size_t base = (size_t)blockIdx.x * NCLS;
    float m = -INFINITY;
    for (int c = tid; c < NCLS; c += 256) m = fmaxf(m, logits[base + c]);
    m = wave_reduce_max(m);
    if ((tid & 63) == 0) sm[tid >> 6] = m;
    __syncthreads();
    m = fmaxf(fmaxf(sm[0], sm[1]), fmaxf(sm[2], sm[3]));
    __syncthreads();

    float s = 0.f, dot = 0.f;
    for (int c = tid; c < NCLS; c += 256) {
        float l = logits[base + c];
        s += expf(l - m);
        dot += labels[base + c] * l;
    }
    s = wave_reduce_sum(s);
    if ((tid & 63) == 0) sm[tid >> 6] = s;
    __syncthreads();
    s = sm[0] + sm[1] + sm[2] + sm[3];
    __syncthreads();
    dot = wave_reduce_sum(dot);
    if ((tid & 63) == 0) sm[tid >> 6] = dot;
    __syncthreads();
    dot = sm[0] + sm[1] + sm[2] + sm[3];

    float inv = 1.f / s;
    for (int c = tid; c < NCLS; c += 256)
        logits[base + c] = expf(logits[base + c] - m) * inv;
    if (tid == 0) rowloss[blockIdx.x] = (m + logf(s)) - dot;
}

__launch_bounds__(256)
__global__ void loss_reduce(const float* __restrict__ rowloss, float* __restrict__ out) {
    __shared__ float sm[4];
    float s = 0.f;
    for (int i = threadIdx.x; i < ROWS; i += 256) s += rowloss[i];
    s = wave_reduce_sum(s);
    if ((threadIdx.x & 63) == 0) sm[threadIdx.x >> 6] = s;
    __syncthreads();
    if (threadIdx.x == 0) out[0] = (sm[0] + sm[1] + sm[2] + sm[3]) * (1.f / ROWS);
}

// ---- launcher ------------------------------------------------------------
extern "C" void kernel_launch(void* const* d_in, const int* in_sizes, int n_in,
                              void* d_out, int out_size, void* d_ws, size_t ws_size,
                              hipStream_t stream) {
    const float* inputs = (const float*)d_in[0];
    const float* labels = (const float*)d_in[1];
    const float* c0     = (const float*)d_in[2];   // initial_state (cell)
    const float* h0     = (const float*)d_in[3];   // initial_output (hidden)
    const float* Wx     = (const float*)d_in[4];
    const float* Wh     = (const float*)d_in[5];
    const float* bias   = (const float*)d_in[6];
    const float* Wo     = (const float*)d_in[7];
    const float* bo     = (const float*)d_in[8];
    float* out = (float*)d_out;

    float* ws = (float*)d_ws;
    float* bp       = ws;                                  // 2048 f32
    float* rowloss  = bp + 2048;                           // 16384 f32
    unsigned short* WhT = (unsigned short*)(rowloss + 16384); // 2048*512
    unsigned short* WxT = WhT + 1048576;                   // 2048*256
    unsigned short* Xb  = WxT + 524288;                    // 16384*256
    unsigned short* h0b = Xb + 4194304;                    // 64*512
    unsigned short* hsb = h0b + 32768;                     // 16384*512
    unsigned short* WoT = hsb + 8388608;                   // 10112*512
    unsigned short* ZxT = WoT + 5177344;                   // 256*2048*64
    // total ~106 MB

    f32_to_bf16<<<(ROWS * DIN / 4 + 255) / 256, 256, 0, stream>>>(inputs, Xb, ROWS * DIN / 4);
    f32_to_bf16<<<(BATCH * DSTATE / 4 + 255) / 256, 256, 0, stream>>>(h0, h0b, BATCH * DSTATE / 4);
    build_wT<<<(NGATE * DSTATE + 255) / 256, 256, 0, stream>>>(Wh, WhT, 9, NGATE * DSTATE);
    build_wT<<<(NGATE * DIN + 255) / 256, 256, 0, stream>>>(Wx, WxT, 8, NGATE * DIN);
    build_bias<<<(NGATE + 255) / 256, 256, 0, stream>>>(bias, bp);
    transpose_wo<<<dim3(NCLS_PAD / 64, DSTATE / 64), 256, 0, stream>>>(Wo, WoT);

    zx_gemm<<<dim3(T_STEPS, NGATE / 128), 256, 0, stream>>>(Xb, WxT, bp, ZxT);

    void* args[] = {(void*)&h0b, (void*)&c0, (void*)&WhT, (void*)&ZxT, (void*)&hsb};
    hipLaunchCooperativeKernel((const void*)lstm_scan_mfma, dim3(64), dim3(256),
                               args, 0, stream);

    gemm_logits_mfma<<<dim3(NCLS_PAD / 128, ROWS / 128), 256, 0, stream>>>(hsb, WoT, bo, out);
    softmax_loss<<<ROWS, 256, 0, stream>>>(out, labels, rowloss);
    loss_reduce<<<1, 256, 0, stream>>>(rowloss, out + (size_t)ROWS * NCLS);
}

// Round 4
// 2498.358 us; speedup vs baseline: 10.5200x; 1.5631x over previous
//
#include <hip/hip_runtime.h>
#include <hip/hip_bf16.h>
#include <math.h>

#define T_STEPS 256
#define BATCH 64
#define DIN 256
#define DSTATE 512
#define NGATE 2048   // 4*DSTATE
#define NCLS 10000
#define NCLS_PAD 10112   // 79 * 128
#define ROWS 16384   // T_STEPS*BATCH
#define SCAN_BLOCKS 64

typedef __attribute__((ext_vector_type(8))) short bf16x8;
typedef __attribute__((ext_vector_type(4))) float f32x4;

__device__ inline unsigned short f2b(float x) {
    __hip_bfloat16 h = __float2bfloat16(x);
    return *(unsigned short*)&h;
}
__device__ inline float b2f(unsigned short u) {
    return __uint_as_float(((unsigned int)u) << 16);
}

// ---- prep kernels -------------------------------------------------------

__global__ void init_bar(unsigned* __restrict__ bar) {
    bar[threadIdx.x] = 0u;   // 64 words: bar[0]=counter, bar[32]=generation flag
}

// vectorized f32 -> bf16 (n multiple of 4)
__global__ void f32_to_bf16(const float* __restrict__ in, unsigned short* __restrict__ out, int n4) {
    int i = blockIdx.x * 256 + threadIdx.x;
    if (i >= n4) return;
    float4 v = *(const float4*)&in[i * 4];
    ushort4 o;
    o.x = f2b(v.x); o.y = f2b(v.y); o.z = f2b(v.z); o.w = f2b(v.w);
    *(ushort4*)&out[i * 4] = o;
}

// WT[jp*K + k] = bf16(W[k*2048 + (jp&3)*512 + (jp>>2)])   (permute + transpose + cvt)
__global__ void build_wT(const float* __restrict__ W, unsigned short* __restrict__ WT,
                         int kshift, int total) {
    int e = blockIdx.x * 256 + threadIdx.x;
    if (e >= total) return;
    int jp = e >> kshift;
    int k = e & ((1 << kshift) - 1);
    int s = jp >> 2, g = jp & 3;
    WT[e] = f2b(W[(size_t)k * NGATE + g * DSTATE + s]);
}

__global__ void build_bias(const float* __restrict__ b, float* __restrict__ bp) {
    int jp = blockIdx.x * 256 + threadIdx.x;
    if (jp >= NGATE) return;
    bp[jp] = b[(jp & 3) * DSTATE + (jp >> 2)];
}

// Tiled transpose + bf16 convert: WoT[n][k] = bf16(Wo[k][n]), n padded to NCLS_PAD with zeros.
__launch_bounds__(256)
__global__ void transpose_wo(const float* __restrict__ Wo, unsigned short* __restrict__ WoT) {
    __shared__ float tile[64][65];
    const int tid = threadIdx.x;
    const int n0 = blockIdx.x * 64, k0 = blockIdx.y * 64;
    #pragma unroll
    for (int r = 0; r < 16; ++r) {
        int k = (tid >> 6) + r * 4;
        int n = tid & 63;
        float v = (n0 + n < NCLS) ? Wo[(size_t)(k0 + k) * NCLS + n0 + n] : 0.f;
        tile[k][n] = v;
    }
    __syncthreads();
    #pragma unroll
    for (int r = 0; r < 16; ++r) {
        int n = (tid >> 6) + r * 4;
        int k = tid & 63;
        WoT[(size_t)(n0 + n) * DSTATE + k0 + k] = f2b(tile[k][n]);
    }
}

// ---- Zx = X @ Wx (+bias), output transposed: ZxT[t][jp][b] bf16 ---------
__launch_bounds__(256)
__global__ void zx_gemm(const unsigned short* __restrict__ Xb,   // [16384][256]
                        const unsigned short* __restrict__ WxT,  // [2048][256]
                        const float* __restrict__ bp,            // [2048]
                        unsigned short* __restrict__ ZxT) {      // [256][2048][64]
    __shared__ unsigned short As[64][264];
    __shared__ unsigned short Bs[128][264];
    __shared__ float zls[4][32][65];
    const int tid = threadIdx.x;
    const int t = blockIdx.x;
    const int n0 = blockIdx.y * 128;
    const int wave = tid >> 6, lane = tid & 63, mr = lane & 15, g = lane >> 4;

    #pragma unroll
    for (int r = 0; r < 8; ++r) {
        int c = r * 256 + tid; int row = c >> 5, q = c & 31;
        *(int4*)&As[row][q * 8] = *(const int4*)&Xb[((size_t)t * 64 + row) * DIN + q * 8];
    }
    #pragma unroll
    for (int r = 0; r < 16; ++r) {
        int c = r * 256 + tid; int row = c >> 5, q = c & 31;
        *(int4*)&Bs[row][q * 8] = *(const int4*)&WxT[(size_t)(n0 + row) * DIN + q * 8];
    }
    __syncthreads();

    f32x4 acc[4][2] = {};
    #pragma unroll
    for (int kt = 0; kt < DIN; kt += 32) {
        bf16x8 af[4], bf[2];
        #pragma unroll
        for (int fm = 0; fm < 4; ++fm) af[fm] = *(const bf16x8*)&As[fm * 16 + mr][kt + g * 8];
        #pragma unroll
        for (int fn = 0; fn < 2; ++fn) bf[fn] = *(const bf16x8*)&Bs[wave * 32 + fn * 16 + mr][kt + g * 8];
        #pragma unroll
        for (int fm = 0; fm < 4; ++fm)
            #pragma unroll
            for (int fn = 0; fn < 2; ++fn)
                acc[fm][fn] = __builtin_amdgcn_mfma_f32_16x16x32_bf16(af[fm], bf[fn], acc[fm][fn], 0, 0, 0);
    }
    #pragma unroll
    for (int fm = 0; fm < 4; ++fm)
        #pragma unroll
        for (int fn = 0; fn < 2; ++fn)
            #pragma unroll
            for (int r = 0; r < 4; ++r)
                zls[wave][fn * 16 + mr][fm * 16 + g * 4 + r] = acc[fm][fn][r];
    #pragma unroll 4
    for (int jr = 0; jr < 32; ++jr) {
        int j = n0 + wave * 32 + jr;
        float v = zls[wave][jr][lane] + bp[j];
        ZxT[((size_t)t * NGATE + j) * 64 + lane] = f2b(v);
    }
}

// ---- custom agent-scope grid barrier ------------------------------------
__device__ __forceinline__ void gridbar(unsigned* cnt, unsigned* flg, unsigned want, int tid) {
    __syncthreads();   // drains vmcnt: all h-stores of this block are in L2
    if (tid == 0) {
        unsigned old = __hip_atomic_fetch_add(cnt, 1u, __ATOMIC_ACQ_REL, __HIP_MEMORY_SCOPE_AGENT);
        if (old == SCAN_BLOCKS - 1) {
            // all other blocks' release-halves happened-before our RMW; our acquire-half
            // (buffer_inv) makes their h visible. Reset counter, then publish generation.
            __hip_atomic_store(cnt, 0u, __ATOMIC_RELAXED, __HIP_MEMORY_SCOPE_AGENT);
            __hip_atomic_store(flg, want, __ATOMIC_RELEASE, __HIP_MEMORY_SCOPE_AGENT);
        } else {
            while (__hip_atomic_load(flg, __ATOMIC_RELAXED, __HIP_MEMORY_SCOPE_AGENT) < want) {}
            (void)__hip_atomic_load(flg, __ATOMIC_ACQUIRE, __HIP_MEMORY_SCOPE_AGENT);
        }
    }
    __syncthreads();
}

// ---- cooperative LSTM scan (MFMA), 64 blocks x 256 threads ---------------
__launch_bounds__(256, 1)
__global__ void lstm_scan_mfma(const unsigned short* __restrict__ h0b,  // [64][512] bf16
                               const float* __restrict__ c0,            // [64][512] f32
                               const unsigned short* __restrict__ WhT,  // [2048][512] bf16
                               const unsigned short* __restrict__ ZxT,  // [256][2048][64] bf16
                               unsigned short* __restrict__ hsb,        // [256][64][512] bf16
                               unsigned* __restrict__ bar) {
    __shared__ unsigned short Wl[32][520];
    __shared__ unsigned short hT[64][520];
    __shared__ float zb[64][33];
    const int tid = threadIdx.x;
    const int bid = blockIdx.x;
    const int j0 = bid * 32;
    const int s0 = bid * 8;
    const int wave = tid >> 6, lane = tid & 63, mr = lane & 15, g = lane >> 4;
    unsigned* bcnt = bar;
    unsigned* bflg = bar + 32;

    #pragma unroll
    for (int r = 0; r < 8; ++r) {
        int c = r * 256 + tid; int row = c >> 6, q = c & 63;
        *(int4*)&Wl[row][q * 8] = *(const int4*)&WhT[(size_t)(j0 + row) * DSTATE + q * 8];
    }

    const int gb = tid >> 2;
    const int sl0 = (tid & 3) * 2;
    float creg0 = c0[gb * DSTATE + s0 + sl0];
    float creg1 = c0[gb * DSTATE + s0 + sl0 + 1];
    __syncthreads();

    // software-pipelined Zx accumulator-init loads
    const size_t zo0 = ((size_t)(j0 + mr)) * 64 + wave * 16 + g * 4;
    const size_t zo1 = ((size_t)(j0 + 16 + mr)) * 64 + wave * 16 + g * 4;
    ushort4 za0 = *(const ushort4*)&ZxT[zo0];
    ushort4 za1 = *(const ushort4*)&ZxT[zo1];

    for (int t = 0; t < T_STEPS; ++t) {
        const unsigned short* hsrc = t ? (hsb + (size_t)(t - 1) * BATCH * DSTATE) : h0b;
        #pragma unroll
        for (int r = 0; r < 16; ++r) {
            int c = r * 256 + tid; int row = c >> 6, q = c & 63;
            *(int4*)&hT[row][q * 8] = *(const int4*)&hsrc[(size_t)row * DSTATE + q * 8];
        }
        __syncthreads();

        f32x4 acc0, acc1;
        acc0[0] = b2f(za0.x); acc0[1] = b2f(za0.y); acc0[2] = b2f(za0.z); acc0[3] = b2f(za0.w);
        acc1[0] = b2f(za1.x); acc1[1] = b2f(za1.y); acc1[2] = b2f(za1.z); acc1[3] = b2f(za1.w);
        if (t + 1 < T_STEPS) {   // prefetch next step's Zx while MFMAs run
            za0 = *(const ushort4*)&ZxT[(size_t)(t + 1) * NGATE * 64 + zo0];
            za1 = *(const ushort4*)&ZxT[(size_t)(t + 1) * NGATE * 64 + zo1];
        }
        #pragma unroll
        for (int kt = 0; kt < DSTATE; kt += 32) {
            bf16x8 af = *(const bf16x8*)&hT[wave * 16 + mr][kt + g * 8];
            acc0 = __builtin_amdgcn_mfma_f32_16x16x32_bf16(af, *(const bf16x8*)&Wl[mr][kt + g * 8], acc0, 0, 0, 0);
            acc1 = __builtin_amdgcn_mfma_f32_16x16x32_bf16(af, *(const bf16x8*)&Wl[16 + mr][kt + g * 8], acc1, 0, 0, 0);
        }
        #pragma unroll
        for (int r = 0; r < 4; ++r) {
            zb[wave * 16 + g * 4 + r][mr] = acc0[r];
            zb[wave * 16 + g * 4 + r][16 + mr] = acc1[r];
        }
        {
            float zi0 = zb[gb][sl0 * 4 + 0], zf0 = zb[gb][sl0 * 4 + 1];
            float zg0 = zb[gb][sl0 * 4 + 2], zo0v = zb[gb][sl0 * 4 + 3];
            float zi1 = zb[gb][sl0 * 4 + 4], zf1 = zb[gb][sl0 * 4 + 5];
            float zg1 = zb[gb][sl0 * 4 + 6], zo1v = zb[gb][sl0 * 4 + 7];
            float i0 = 1.f / (1.f + expf(-zi0)), f0 = 1.f / (1.f + expf(-zf0));
            float o0 = 1.f / (1.f + expf(-zo0v)), g0 = tanhf(zg0);
            float i1 = 1.f / (1.f + expf(-zi1)), f1 = 1.f / (1.f + expf(-zf1));
            float o1 = 1.f / (1.f + expf(-zo1v)), g1 = tanhf(zg1);
            creg0 = f0 * creg0 + i0 * g0;
            creg1 = f1 * creg1 + i1 * g1;
            float h0v = o0 * tanhf(creg0);
            float h1v = o1 * tanhf(creg1);
            ushort2 hv; hv.x = f2b(h0v); hv.y = f2b(h1v);
            *(ushort2*)&hsb[((size_t)t * BATCH + gb) * DSTATE + s0 + sl0] = hv;
        }
        if (t != T_STEPS - 1)
            gridbar(bcnt, bflg, (unsigned)(t + 1), tid);
        // last step: kernel-end implicit release makes hsb visible to next kernel
    }
}

// ---- logits GEMM (unchanged, verified) ----------------------------------
__launch_bounds__(256)
__global__ void gemm_logits_mfma(const unsigned short* __restrict__ A,   // [ROWS][512]
                                 const unsigned short* __restrict__ Bt,  // [NCLS_PAD][512]
                                 const float* __restrict__ bo,
                                 float* __restrict__ C) {
    __shared__ unsigned short As[128][40];
    __shared__ unsigned short Bs[128][40];
    const int tid = threadIdx.x;
    const int wave = tid >> 6, lane = tid & 63;
    const int wm = wave >> 1, wn = wave & 1;
    const int m0 = blockIdx.y * 128, n0 = blockIdx.x * 128;
    const int g = lane >> 4, mr = lane & 15;

    f32x4 acc[4][4] = {};
    for (int kt = 0; kt < DSTATE; kt += 32) {
        #pragma unroll
        for (int r = 0; r < 2; ++r) {
            int c = r * 256 + tid;
            int row = c >> 2, q = c & 3;
            *(int4*)&As[row][q * 8] = *(const int4*)&A[(size_t)(m0 + row) * DSTATE + kt + q * 8];
            *(int4*)&Bs[row][q * 8] = *(const int4*)&Bt[(size_t)(n0 + row) * DSTATE + kt + q * 8];
        }
        __syncthreads();
        bf16x8 af[4], bf[4];
        #pragma unroll
        for (int f = 0; f < 4; ++f) {
            af[f] = *(const bf16x8*)&As[wm * 64 + f * 16 + mr][g * 8];
            bf[f] = *(const bf16x8*)&Bs[wn * 64 + f * 16 + mr][g * 8];
        }
        #pragma unroll
        for (int fm = 0; fm < 4; ++fm)
            #pragma unroll
            for (int fn = 0; fn < 4; ++fn)
                acc[fm][fn] = __builtin_amdgcn_mfma_f32_16x16x32_bf16(af[fm], bf[fn], acc[fm][fn], 0, 0, 0);
        __syncthreads();
    }
    #pragma unroll
    for (int fm = 0; fm < 4; ++fm) {
        #pragma unroll
        for (int fn = 0; fn < 4; ++fn) {
            int col = n0 + wn * 64 + fn * 16 + (lane & 15);
            if (col >= NCLS) continue;
            float bias = bo[col];
            #pragma unroll
            for (int r = 0; r < 4; ++r) {
                int row = m0 + wm * 64 + fm * 16 + (lane >> 4) * 4 + r;
                C[(size_t)row * NCLS + col] = acc[fm][fn][r] + bias;
            }
        }
    }
}

// ---- softmax + loss ------------------------------------------------------
__device__ inline float wave_reduce_max(float v) {
    #pragma unroll
    for (int off = 32; off > 0; off >>= 1) v = fmaxf(v, __shfl_xor(v, off));
    return v;
}
__device__ inline float wave_reduce_sum(float v) {
    #pragma unroll
    for (int off = 32; off > 0; off >>= 1) v += __shfl_xor(v, off);
    return v;
}

__launch_bounds__(256)
__global__ void softmax_loss(float* __restrict__ logits,
                             const float* __restrict__ labels,
                             float* __restrict__ rowloss) {
    __shared__ float sm[4];
    const int tid = threadIdx.x;
    const size_t base = (size_t)blockIdx.x * NCLS;
    float m = -INFINITY;
    for (int c = tid; c < NCLS; c += 256) m = fmaxf(m, logits[base + c]);
    m = wave_reduce_max(m);
    if ((tid & 63) == 0) sm[tid >> 6] = m;
    __syncthreads();
    m = fmaxf(fmaxf(sm[0], sm[1]), fmaxf(sm[2], sm[3]));
    __syncthreads();

    float s = 0.f, dot = 0.f;
    for (int c = tid; c < NCLS; c += 256) {
        float l = logits[base + c];
        s += expf(l - m);
        dot += labels[base + c] * l;
    }
    s = wave_reduce_sum(s);
    if ((tid & 63) == 0) sm[tid >> 6] = s;
    __syncthreads();
    s = sm[0] + sm[1] + sm[2] + sm[3];
    __syncthreads();
    dot = wave_reduce_sum(dot);
    if ((tid & 63) == 0) sm[tid >> 6] = dot;
    __syncthreads();
    dot = sm[0] + sm[1] + sm[2] + sm[3];

    float inv = 1.f / s;
    for (int c = tid; c < NCLS; c += 256)
        logits[base + c] = expf(logits[base + c] - m) * inv;
    if (tid == 0) rowloss[blockIdx.x] = (m + logf(s)) - dot;
}

__launch_bounds__(256)
__global__ void loss_reduce(const float* __restrict__ rowloss, float* __restrict__ out) {
    __shared__ float sm[4];
    float s = 0.f;
    for (int i = threadIdx.x; i < ROWS; i += 256) s += rowloss[i];
    s = wave_reduce_sum(s);
    if ((threadIdx.x & 63) == 0) sm[threadIdx.x >> 6] = s;
    __syncthreads();
    if (threadIdx.x == 0) out[0] = (sm[0] + sm[1] + sm[2] + sm[3]) * (1.f / ROWS);
}

// ---- launcher ------------------------------------------------------------
extern "C" void kernel_launch(void* const* d_in, const int* in_sizes, int n_in,
                              void* d_out, int out_size, void* d_ws, size_t ws_size,
                              hipStream_t stream) {
    const float* inputs = (const float*)d_in[0];
    const float* labels = (const float*)d_in[1];
    const float* c0     = (const float*)d_in[2];   // initial_state (cell)
    const float* h0     = (const float*)d_in[3];   // initial_output (hidden)
    const float* Wx     = (const float*)d_in[4];
    const float* Wh     = (const float*)d_in[5];
    const float* bias   = (const float*)d_in[6];
    const float* Wo     = (const float*)d_in[7];
    const float* bo     = (const float*)d_in[8];
    float* out = (float*)d_out;

    float* ws = (float*)d_ws;
    float* bp       = ws;                                  // 2048 f32
    float* rowloss  = bp + 2048;                           // 16384 f32
    unsigned short* WhT = (unsigned short*)(rowloss + 16384); // 2048*512
    unsigned short* WxT = WhT + 1048576;                   // 2048*256
    unsigned short* Xb  = WxT + 524288;                    // 16384*256
    unsigned short* h0b = Xb + 4194304;                    // 64*512
    unsigned short* hsb = h0b + 32768;                     // 16384*512
    unsigned short* WoT = hsb + 8388608;                   // 10112*512
    unsigned short* ZxT = WoT + 5177344;                   // 256*2048*64
    unsigned* bar = (unsigned*)(ZxT + 33554432);           // 64 words

    init_bar<<<1, 64, 0, stream>>>(bar);
    f32_to_bf16<<<(ROWS * DIN / 4 + 255) / 256, 256, 0, stream>>>(inputs, Xb, ROWS * DIN / 4);
    f32_to_bf16<<<(BATCH * DSTATE / 4 + 255) / 256, 256, 0, stream>>>(h0, h0b, BATCH * DSTATE / 4);
    build_wT<<<(NGATE * DSTATE + 255) / 256, 256, 0, stream>>>(Wh, WhT, 9, NGATE * DSTATE);
    build_wT<<<(NGATE * DIN + 255) / 256, 256, 0, stream>>>(Wx, WxT, 8, NGATE * DIN);
    build_bias<<<(NGATE + 255) / 256, 256, 0, stream>>>(bias, bp);
    transpose_wo<<<dim3(NCLS_PAD / 64, DSTATE / 64), 256, 0, stream>>>(Wo, WoT);

    zx_gemm<<<dim3(T_STEPS, NGATE / 128), 256, 0, stream>>>(Xb, WxT, bp, ZxT);

    void* args[] = {(void*)&h0b, (void*)&c0, (void*)&WhT, (void*)&ZxT, (void*)&hsb, (void*)&bar};
    hipLaunchCooperativeKernel((const void*)lstm_scan_mfma, dim3(SCAN_BLOCKS), dim3(256),
                               args, 0, stream);

    gemm_logits_mfma<<<dim3(NCLS_PAD / 128, ROWS / 128), 256, 0, stream>>>(hsb, WoT, bo, out);
    softmax_loss<<<ROWS, 256, 0, stream>>>(out, labels, rowloss);
    loss_reduce<<<1, 256, 0, stream>>>(rowloss, out + (size_t)ROWS * NCLS);
}